// Round 4
// baseline (119.347 us; speedup 1.0000x reference)
//
#include <hip/hip_runtime.h>

#define DIM   64
#define KCB   1024
#define KT2   128    // codewords per LDS tile (8 tiles)
#define NROW  32768

typedef float floatx4 __attribute__((ext_vector_type(4)));
typedef __bf16 bf16x8 __attribute__((ext_vector_type(8)));
typedef unsigned int uint;

union ABu { bf16x8 v; __bf16 h[8]; uint4 u4; };

// ---------------------------------------------------------------------------
// Prep (codebook only): fp32 codebook -> bf16 rows with 16B-chunk XOR swizzle
// (LDS image) + initv = -0.5*csq - 0.5 (makes every score < 0).
// Widened: 64 blocks, thread = QUARTER codeword (16 elems, 64B coalesced
// read), csq reduced across the 4-lane group -> ~2x lower latency than the
// 16-block version so score starts sooner.
// ---------------------------------------------------------------------------
extern "C" __global__ void __launch_bounds__(256)
vq_prep_cb(const float* __restrict__ cbg, uint* __restrict__ cb_bf,
           float* __restrict__ initv, float* __restrict__ loss)
{
    const int q = blockIdx.x * 256 + threadIdx.x;   // 0..16383 quarter-rows
    const int k = q >> 2;                            // codeword row 0..4095
    const int p = q & 3;                             // quarter within row
    const float4* __restrict__ src = (const float4*)cbg + (size_t)k * 16 + p * 4;
    uint* __restrict__ drow = cb_bf + (size_t)k * 32;
    float csq = 0.f;
    #pragma unroll
    for (int h = 0; h < 2; ++h) {                    // 2 chunks of 8 floats
        const float4 f0 = src[h * 2];
        const float4 f1 = src[h * 2 + 1];
        csq += f0.x*f0.x + f0.y*f0.y + f0.z*f0.z + f0.w*f0.w
             + f1.x*f1.x + f1.y*f1.y + f1.z*f1.z + f1.w*f1.w;
        ABu t;
        t.h[0]=(__bf16)f0.x; t.h[1]=(__bf16)f0.y; t.h[2]=(__bf16)f0.z; t.h[3]=(__bf16)f0.w;
        t.h[4]=(__bf16)f1.x; t.h[5]=(__bf16)f1.y; t.h[6]=(__bf16)f1.z; t.h[7]=(__bf16)f1.w;
        const int c  = p * 2 + h;
        const int dc = c ^ (k & 7);                  // LDS-bank XOR swizzle
        *(uint4*)&drow[dc * 4] = t.u4;
    }
    csq += __shfl_xor(csq, 1);
    csq += __shfl_xor(csq, 2);                       // sum over the 4 quarters
    if (p == 0) initv[k] = -0.5f * csq - 0.5f;
    if (q == 0) *loss = 0.f;
}

// ---------------------------------------------------------------------------
// Fused score+emit: grid 2048 = chunk(9b, 64 rows) | g(2b); 256 thr,
// 16 rows/wave. 4 blocks/CU resident, 2 sequential cohorts -> late blocks'
// latent-read bursts overlap early blocks' MFMA loop + out-write bursts
// (the grid-1024 version ran all phases in lockstep: read burst / compute /
// write burst serialized at ~16-18us vs the 10.7us HBM floor).
// Per block: fp32 latents read direct (coalesced), bf16 A-frags in-register,
// xsq on the fly; 8x KT2=128 double-buffered codebook tiles via
// global_load_lds (next tile issued before current tile's MFMA); packed-key
// argmin in regs; epilogue gathers winning fp32 codeword (L2-resident) and
// writes out + loss. LDS 36.5KB -> 4 blocks/CU.
// ---------------------------------------------------------------------------
extern "C" __global__ void __launch_bounds__(256, 4)
vq_score(const float* __restrict__ latents, const uint* __restrict__ cb_bf,
         const float* __restrict__ initv, const float* __restrict__ cbg,
         float* __restrict__ out, float* __restrict__ loss)
{
    __shared__ __attribute__((aligned(16))) uint  cb_lds[2][KT2 * 32]; // 2x16KB
    __shared__ __attribute__((aligned(16))) float iv_lds[KCB];         // 4 KB
    __shared__ float xsq_lds[64];
    __shared__ float part[4];

    const int tid  = threadIdx.x;
    const int wave = tid >> 6;
    const int lane = tid & 63;
    const int l15  = lane & 15;
    const int quad = lane >> 4;

    const int bid   = blockIdx.x;
    const int chunk = bid & 511;              // bid%8 spreads XCDs; the 4
    const int g     = bid >> 9;               // g-siblings of a chunk are
    const int wRow0 = chunk * 64 + wave * 16; // 512 apart -> same XCD L2

    const uint* gcb = cb_bf + (size_t)g * (KCB * 32);

    // ---- prologue: DMA tile0 (16KB) + initv (4KB); latent loads overlap ----
    {
        #pragma unroll
        for (int i = 0; i < 4; ++i) {
            const int off = wave * 1024 + i * 256;          // uint words
            __builtin_amdgcn_global_load_lds(
                (const __attribute__((address_space(1))) uint*)(gcb + off + lane * 4),
                (__attribute__((address_space(3))) uint*)&cb_lds[0][off], 16, 0, 0);
        }
        const uint* isrc = (const uint*)(initv + g * KCB) + wave * 256;
        __builtin_amdgcn_global_load_lds(
            (const __attribute__((address_space(1))) uint*)(isrc + lane * 4),
            (__attribute__((address_space(3))) uint*)&iv_lds[wave * 256], 16, 0, 0);
    }

    // ---- A fragments from fp32 latents + xsq, all in-register ----
    bf16x8 afrag[2];
    {
        const float4* __restrict__ lsrc = (const float4*)latents;
        const size_t rb = (size_t)(wRow0 + l15) * 64 + g * 16 + (size_t)quad * 2;
        float s = 0.f;
        #pragma unroll
        for (int ks = 0; ks < 2; ++ks) {
            const float4 f0 = lsrc[rb + ks * 8];
            const float4 f1 = lsrc[rb + ks * 8 + 1];
            s += f0.x*f0.x + f0.y*f0.y + f0.z*f0.z + f0.w*f0.w
               + f1.x*f1.x + f1.y*f1.y + f1.z*f1.z + f1.w*f1.w;
            ABu t;
            t.h[0]=(__bf16)f0.x; t.h[1]=(__bf16)f0.y; t.h[2]=(__bf16)f0.z; t.h[3]=(__bf16)f0.w;
            t.h[4]=(__bf16)f1.x; t.h[5]=(__bf16)f1.y; t.h[6]=(__bf16)f1.z; t.h[7]=(__bf16)f1.w;
            afrag[ks] = t.v;
        }
        s += __shfl_xor(s, 16);
        s += __shfl_xor(s, 32);               // full 64-dim row sum, all quads
        if (quad == 0) xsq_lds[wave * 16 + l15] = s;
    }
    __syncthreads();                          // tile0 + iv + xsq ready

    uint best[4] = { 0xFFFFFFFFu, 0xFFFFFFFFu, 0xFFFFFFFFu, 0xFFFFFFFFu };

    const int o0  = l15 * 32;
    const int sw0 = (quad       ^ (l15 & 7)) << 2;
    const int sw1 = ((quad + 4) ^ (l15 & 7)) << 2;

    #pragma unroll
    for (int tile = 0; tile < 8; ++tile) {
        // issue next tile's DMA first: overlaps the MFMA below
        if (tile < 7) {
            const uint* gsrc = gcb + (tile + 1) * (KT2 * 32);
            #pragma unroll
            for (int i = 0; i < 4; ++i) {
                const int off = wave * 1024 + i * 256;
                __builtin_amdgcn_global_load_lds(
                    (const __attribute__((address_space(1))) uint*)(gsrc + off + lane * 4),
                    (__attribute__((address_space(3))) uint*)&cb_lds[(tile + 1) & 1][off], 16, 0, 0);
            }
        }

        const uint*  bbase0 = &cb_lds[tile & 1][o0 + sw0];
        const uint*  bbase1 = &cb_lds[tile & 1][o0 + sw1];
        const float* ivb    = &iv_lds[tile * KT2 + l15];
        const uint   kcol0  = (uint)(tile * KT2 + l15);

        #pragma unroll 4
        for (int t = 0; t < 8; ++t) {
            const float v = ivb[t * 16];
            ABu b0, b1;
            b0.u4 = *(const uint4*)(bbase0 + t * 512);
            b1.u4 = *(const uint4*)(bbase1 + t * 512);
            const uint kcol = kcol0 + t * 16;
            const floatx4 accb = { v, v, v, v };   // shared C operand (D != C)
            floatx4 acc = __builtin_amdgcn_mfma_f32_16x16x32_bf16(afrag[0], b0.v, accb, 0, 0, 0);
            acc = __builtin_amdgcn_mfma_f32_16x16x32_bf16(afrag[1], b1.v, acc, 0, 0, 0);
            // score < 0 -> fp32 bits monotone decreasing; pack idx, min_u32
            #pragma unroll
            for (int r = 0; r < 4; ++r) {
                const uint key = (__float_as_uint(acc[r]) & 0xFFFFFC00u) | kcol;
                best[r] = best[r] < key ? best[r] : key;
            }
        }
        __syncthreads();   // drains next-tile DMA (vmcnt) + frees read buffer
    }

    // ---- epilogue: 16-lane argmin reduce -> gather fp32 codeword -> out ----
    float lsum = 0.f;
    const float4* __restrict__ cb4 = (const float4*)cbg + (size_t)g * (KCB * 16);
    float4* __restrict__ out4 = (float4*)out;
    #pragma unroll
    for (int r = 0; r < 4; ++r) {
        uint kmin = best[r];
        #pragma unroll
        for (int m = 1; m <= 8; m <<= 1) {
            const uint o = (uint)__shfl_xor((int)kmin, m);
            kmin = o < kmin ? o : kmin;
        }
        const int bl   = wave * 16 + quad * 4 + r;            // block row
        const int n    = chunk * 64 + bl;                     // global row
        const int kidx = (int)(kmin & 1023u);
        // 16 lanes x float4 = 256B contiguous write of this (n,g) slice
        out4[(size_t)n * 64 + g * 16 + l15] = cb4[(size_t)kidx * 16 + l15];
        if (l15 == 0) {
            const float sc = __uint_as_float(kmin & 0xFFFFFC00u);
            lsum += xsq_lds[bl] - 2.f * sc - 1.f;   // exact squared dist
        }
    }
    lsum += __shfl_xor(lsum, 16);
    lsum += __shfl_xor(lsum, 32);             // sum the 4 quad partials
    if (lane == 0) part[wave] = lsum;
    __syncthreads();
    if (tid == 0)
        atomicAdd(loss, (part[0] + part[1] + part[2] + part[3]) * (1.25f / 8388608.0f));
}

extern "C" void kernel_launch(void* const* d_in, const int* in_sizes, int n_in,
                              void* d_out, int out_size, void* d_ws, size_t ws_size,
                              hipStream_t stream)
{
    const float* latents = (const float*)d_in[0];
    const float* cbg     = (const float*)d_in[1];
    float* out   = (float*)d_out;
    float* lossp = out + 8388608;

    uint*  cb_bf = (uint*)d_ws;                          // 512 KB
    float* initv = (float*)((uint*)d_ws + 4096 * 32);    // 16 KB

    vq_prep_cb<<<dim3(64),   dim3(256), 0, stream>>>(cbg, cb_bf, initv, lossp);
    vq_score  <<<dim3(2048), dim3(256), 0, stream>>>(latents, cb_bf, initv,
                                                     cbg, out, lossp);
}

// Round 5
// 111.976 us; speedup vs baseline: 1.0658x; 1.0658x over previous
//
#include <hip/hip_runtime.h>

#define DIM   64
#define KCB   1024
#define KT2   128    // codewords per LDS tile (8 tiles)
#define NROW  32768

typedef float floatx4 __attribute__((ext_vector_type(4)));
typedef __bf16 bf16x8 __attribute__((ext_vector_type(8)));
typedef unsigned int uint;

union ABu { bf16x8 v; __bf16 h[8]; uint4 u4; };

// ---------------------------------------------------------------------------
// Prep (codebook only): fp32 codebook -> bf16 rows with 16B-chunk XOR swizzle
// (LDS image) + initv = -0.5*csq - 0.5 (makes every score < 0).
// 64 blocks, thread = QUARTER codeword (16 elems), csq via 4-lane shfl.
// ---------------------------------------------------------------------------
extern "C" __global__ void __launch_bounds__(256)
vq_prep_cb(const float* __restrict__ cbg, uint* __restrict__ cb_bf,
           float* __restrict__ initv, float* __restrict__ loss)
{
    const int q = blockIdx.x * 256 + threadIdx.x;   // 0..16383 quarter-rows
    const int k = q >> 2;                            // codeword row 0..4095
    const int p = q & 3;                             // quarter within row
    const float4* __restrict__ src = (const float4*)cbg + (size_t)k * 16 + p * 4;
    uint* __restrict__ drow = cb_bf + (size_t)k * 32;
    float csq = 0.f;
    #pragma unroll
    for (int h = 0; h < 2; ++h) {                    // 2 chunks of 8 floats
        const float4 f0 = src[h * 2];
        const float4 f1 = src[h * 2 + 1];
        csq += f0.x*f0.x + f0.y*f0.y + f0.z*f0.z + f0.w*f0.w
             + f1.x*f1.x + f1.y*f1.y + f1.z*f1.z + f1.w*f1.w;
        ABu t;
        t.h[0]=(__bf16)f0.x; t.h[1]=(__bf16)f0.y; t.h[2]=(__bf16)f0.z; t.h[3]=(__bf16)f0.w;
        t.h[4]=(__bf16)f1.x; t.h[5]=(__bf16)f1.y; t.h[6]=(__bf16)f1.z; t.h[7]=(__bf16)f1.w;
        const int c  = p * 2 + h;
        const int dc = c ^ (k & 7);                  // LDS-bank XOR swizzle
        *(uint4*)&drow[dc * 4] = t.u4;
    }
    csq += __shfl_xor(csq, 1);
    csq += __shfl_xor(csq, 2);                       // sum over the 4 quarters
    if (p == 0) initv[k] = -0.5f * csq - 0.5f;
    if (q == 0) *loss = 0.f;
}

// ---------------------------------------------------------------------------
// Fused score+emit, rt=4 B-reuse restored. Grid 512 = chunk(7b, 256 rows) |
// g(2b); 256 thr, 64 rows/wave (4 row-tiles in regs).
// WHY rt=4: round-4 counters showed LDS-read-throughput-bound (hbm 14%,
// Mfma 12.5%, VALU 35%): 2 ds_read_b128 fed only 2 MFMAs -> 61K LDS cyc/CU
// (25.6us). With rt=4, the same 2 b128 feed 8 MFMAs: LDS 15K cyc/CU (6.4us)
// < MFMA 19.9K (8.3us) -> matrix pipe becomes critical, HBM floor 10.6us.
// Per block: fp32 latents direct (coalesced 16B/lane), bf16 A-frags + xsq
// in-register; 8x KT2=128 double-buffered codebook tiles via global_load_lds
// (next tile issued before current tile's MFMA); packed-key argmin in regs;
// epilogue gathers winning fp32 codeword (L2) -> out + loss.
// LDS 37.4KB; grid 512 = 2 blocks/CU, one cohort.
// ---------------------------------------------------------------------------
extern "C" __global__ void __launch_bounds__(256, 2)
vq_score(const float* __restrict__ latents, const uint* __restrict__ cb_bf,
         const float* __restrict__ initv, const float* __restrict__ cbg,
         float* __restrict__ out, float* __restrict__ loss)
{
    __shared__ __attribute__((aligned(16))) uint  cb_lds[2][KT2 * 32]; // 2x16KB
    __shared__ __attribute__((aligned(16))) float iv_lds[KCB];         // 4 KB
    __shared__ float xsq_lds[256];                                     // 1 KB
    __shared__ float part[4];

    const int tid  = threadIdx.x;
    const int wave = tid >> 6;
    const int lane = tid & 63;
    const int l15  = lane & 15;
    const int quad = lane >> 4;

    const int bid   = blockIdx.x;
    const int chunk = bid & 127;              // bid%8 spreads chunks over XCDs
    const int g     = bid >> 7;
    const int wRow0 = chunk * 256 + wave * 64;

    const uint* gcb = cb_bf + (size_t)g * (KCB * 32);

    // ---- prologue: DMA tile0 (16KB) + initv (4KB); latent loads overlap ----
    {
        #pragma unroll
        for (int i = 0; i < 4; ++i) {
            const int off = wave * 1024 + i * 256;          // uint words
            __builtin_amdgcn_global_load_lds(
                (const __attribute__((address_space(1))) uint*)(gcb + off + lane * 4),
                (__attribute__((address_space(3))) uint*)&cb_lds[0][off], 16, 0, 0);
        }
        const uint* isrc = (const uint*)(initv + g * KCB) + wave * 256;
        __builtin_amdgcn_global_load_lds(
            (const __attribute__((address_space(1))) uint*)(isrc + lane * 4),
            (__attribute__((address_space(3))) uint*)&iv_lds[wave * 256], 16, 0, 0);
    }

    // ---- A fragments from fp32 latents + xsq, all in-register ----
    // per rt: wave instr pair covers 16 rows x 128B (quads at 32B stride)
    bf16x8 afrag[4][2];
    {
        const float4* __restrict__ lsrc = (const float4*)latents;
        #pragma unroll
        for (int rt = 0; rt < 4; ++rt) {
            const size_t rb = (size_t)(wRow0 + rt * 16 + l15) * 64 + g * 16
                            + (size_t)quad * 2;
            float s = 0.f;
            #pragma unroll
            for (int ks = 0; ks < 2; ++ks) {
                const float4 f0 = lsrc[rb + ks * 8];
                const float4 f1 = lsrc[rb + ks * 8 + 1];
                s += f0.x*f0.x + f0.y*f0.y + f0.z*f0.z + f0.w*f0.w
                   + f1.x*f1.x + f1.y*f1.y + f1.z*f1.z + f1.w*f1.w;
                ABu t;
                t.h[0]=(__bf16)f0.x; t.h[1]=(__bf16)f0.y; t.h[2]=(__bf16)f0.z; t.h[3]=(__bf16)f0.w;
                t.h[4]=(__bf16)f1.x; t.h[5]=(__bf16)f1.y; t.h[6]=(__bf16)f1.z; t.h[7]=(__bf16)f1.w;
                afrag[rt][ks] = t.v;
            }
            s += __shfl_xor(s, 16);
            s += __shfl_xor(s, 32);           // full 64-dim row sum, all quads
            if (quad == 0) xsq_lds[wave * 64 + rt * 16 + l15] = s;
        }
    }
    __syncthreads();                          // tile0 + iv + xsq ready

    uint best[4][4];
    #pragma unroll
    for (int rt = 0; rt < 4; ++rt)
        #pragma unroll
        for (int r = 0; r < 4; ++r) best[rt][r] = 0xFFFFFFFFu;

    const int o0  = l15 * 32;
    const int sw0 = (quad       ^ (l15 & 7)) << 2;
    const int sw1 = ((quad + 4) ^ (l15 & 7)) << 2;

    #pragma unroll
    for (int tile = 0; tile < 8; ++tile) {
        // issue next tile's DMA first: overlaps the MFMA below
        if (tile < 7) {
            const uint* gsrc = gcb + (tile + 1) * (KT2 * 32);
            #pragma unroll
            for (int i = 0; i < 4; ++i) {
                const int off = wave * 1024 + i * 256;
                __builtin_amdgcn_global_load_lds(
                    (const __attribute__((address_space(1))) uint*)(gsrc + off + lane * 4),
                    (__attribute__((address_space(3))) uint*)&cb_lds[(tile + 1) & 1][off], 16, 0, 0);
            }
        }

        const uint*  bbase0 = &cb_lds[tile & 1][o0 + sw0];
        const uint*  bbase1 = &cb_lds[tile & 1][o0 + sw1];
        const float* ivb    = &iv_lds[tile * KT2 + l15];
        const uint   kcol0  = (uint)(tile * KT2 + l15);

        #pragma unroll 2
        for (int t = 0; t < 8; ++t) {
            const float v = ivb[t * 16];
            ABu b0, b1;
            b0.u4 = *(const uint4*)(bbase0 + t * 512);
            b1.u4 = *(const uint4*)(bbase1 + t * 512);
            const uint kcol = kcol0 + t * 16;
            const floatx4 accb = { v, v, v, v };   // shared C operand (D != C)
            #pragma unroll
            for (int rt = 0; rt < 4; ++rt) {
                floatx4 acc = __builtin_amdgcn_mfma_f32_16x16x32_bf16(afrag[rt][0], b0.v, accb, 0, 0, 0);
                acc = __builtin_amdgcn_mfma_f32_16x16x32_bf16(afrag[rt][1], b1.v, acc, 0, 0, 0);
                // score < 0 -> fp32 bits monotone decreasing; pack idx, min_u32
                #pragma unroll
                for (int r = 0; r < 4; ++r) {
                    const uint key = (__float_as_uint(acc[r]) & 0xFFFFFC00u) | kcol;
                    best[rt][r] = best[rt][r] < key ? best[rt][r] : key;
                }
            }
        }
        __syncthreads();   // drains next-tile DMA (vmcnt) + frees read buffer
    }

    // ---- epilogue: 16-lane argmin reduce -> gather fp32 codeword -> out ----
    float lsum = 0.f;
    const float4* __restrict__ cb4 = (const float4*)cbg + (size_t)g * (KCB * 16);
    float4* __restrict__ out4 = (float4*)out;
    #pragma unroll
    for (int rt = 0; rt < 4; ++rt)
        #pragma unroll
        for (int r = 0; r < 4; ++r) {
            uint kmin = best[rt][r];
            #pragma unroll
            for (int m = 1; m <= 8; m <<= 1) {
                const uint o = (uint)__shfl_xor((int)kmin, m);
                kmin = o < kmin ? o : kmin;
            }
            const int bl   = wave * 64 + rt * 16 + quad * 4 + r;  // block row
            const int n    = chunk * 256 + bl;                    // global row
            const int kidx = (int)(kmin & 1023u);
            // 16 lanes x float4 = 256B contiguous write of this (n,g) slice
            out4[(size_t)n * 64 + g * 16 + l15] = cb4[(size_t)kidx * 16 + l15];
            if (l15 == 0) {
                const float sc = __uint_as_float(kmin & 0xFFFFFC00u);
                lsum += xsq_lds[bl] - 2.f * sc - 1.f;   // exact squared dist
            }
        }
    lsum += __shfl_xor(lsum, 16);
    lsum += __shfl_xor(lsum, 32);             // sum the 4 quad partials
    if (lane == 0) part[wave] = lsum;
    __syncthreads();
    if (tid == 0)
        atomicAdd(loss, (part[0] + part[1] + part[2] + part[3]) * (1.25f / 8388608.0f));
}

extern "C" void kernel_launch(void* const* d_in, const int* in_sizes, int n_in,
                              void* d_out, int out_size, void* d_ws, size_t ws_size,
                              hipStream_t stream)
{
    const float* latents = (const float*)d_in[0];
    const float* cbg     = (const float*)d_in[1];
    float* out   = (float*)d_out;
    float* lossp = out + 8388608;

    uint*  cb_bf = (uint*)d_ws;                          // 512 KB
    float* initv = (float*)((uint*)d_ws + 4096 * 32);    // 16 KB

    vq_prep_cb<<<dim3(64),  dim3(256), 0, stream>>>(cbg, cb_bf, initv, lossp);
    vq_score  <<<dim3(512), dim3(256), 0, stream>>>(latents, cb_bf, initv,
                                                    cbg, out, lossp);
}